// Round 9
// baseline (576.992 us; speedup 1.0000x reference)
//
#include <hip/hip_runtime.h>
#include <math.h>

#define NMAPS 16
#define DIN 512
#define DOUT 128
#define QD 64

typedef __attribute__((ext_vector_type(8))) short bf16x8;  // 8 bf16 (4 VGPR)
typedef __attribute__((ext_vector_type(4))) float f32x4;

// bf16 split helpers (RNE). x = bf2f(hi) + bf2f(lo) + O(2^-18 |x|).
__device__ __forceinline__ unsigned short f2bf(float x) {
  unsigned int u = __float_as_uint(x);
  return (unsigned short)((u + 0x7FFFu + ((u >> 16) & 1u)) >> 16);
}
__device__ __forceinline__ float bf2f(unsigned short h) {
  return __uint_as_float(((unsigned int)h) << 16);
}

// DPP quad broadcast (lane quadbase+Q); bitwise == __shfl(x, lb+Q).
template <int CTRL>
__device__ __forceinline__ float qbc(float x) {
  return __int_as_float(__builtin_amdgcn_update_dpp(
      0, __float_as_int(x), CTRL, 0xF, 0xF, true));
}
__device__ __forceinline__ float quadSum4(float x) {
  float s0 = qbc<0x00>(x), s1 = qbc<0x55>(x);
  float s2 = qbc<0xAA>(x), s3 = qbc<0xFF>(x);
  return ((s0 + s1) + s2) + s3;
}

// slarfg sign convention (LAPACK) — unchanged since R4.
__device__ __forceinline__ void make_tau(float xn2, float alpha, float& tau,
                                         float& invs) {
  if (xn2 == 0.f) { tau = 0.f; invs = 0.f; }
  else {
    float mag = sqrtf(alpha * alpha + xn2);
    float beta = (alpha >= 0.f) ? -mag : mag;
    tau = (beta - alpha) / beta;
    invs = 1.f / (alpha - beta);
  }
}

// Tree dot: 4 blocked chains of 8 + ordered combine (critical path ~45 cyc
// vs 128 for the single 32-chain). Changes rounding vs R4-R8 (accepted).
__device__ __forceinline__ float tree_dot(const float (&x)[32],
                                          const float (&y)[32]) {
  float pp[4] = {0.f, 0.f, 0.f, 0.f};
#pragma unroll
  for (int q = 0; q < 4; ++q)
#pragma unroll
    for (int k = 0; k < 8; ++k)
      pp[q] = fmaf(x[8 * q + k], y[8 * q + k], pp[q]);
  return ((pp[0] + pp[1]) + pp[2]) + pp[3];
}

template <bool SCALE>
__device__ __forceinline__ void publish_col(float (&a)[32], const int t,
                                            const int piv, const float invs,
                                            float* __restrict__ Vrow) {
#pragma unroll
  for (int k4 = 0; k4 < 8; ++k4) {
    float4 v4;
    float* vv = (float*)&v4;
#pragma unroll
    for (int e = 0; e < 4; ++e) {
      int k = 4 * k4 + e;
      int r = t + 4 * k;
      float nv;
      if (r > piv) {
        if (SCALE) a[k] *= invs;
        nv = a[k];
      } else nv = (r == piv) ? 1.f : 0.f;
      vv[e] = nv;
    }
    *(float4*)&Vrow[4 * k4] = v4;
  }
}

__device__ __forceinline__ void load_v(float (&vr)[32],
                                       const float* __restrict__ Vrow) {
#pragma unroll
  for (int k4 = 0; k4 < 8; ++k4) {
    float4 v4 = *(const float4*)&Vrow[4 * k4];
    vr[4 * k4 + 0] = v4.x; vr[4 * k4 + 1] = v4.y;
    vr[4 * k4 + 2] = v4.z; vr[4 * k4 + 3] = v4.w;
  }
}

// Masked norm^2 over rows r > piv, tree-reduced; also extracts a[.] at r==piv+0
// (the next pivot alpha) via the caller's static-index loop.
__device__ __forceinline__ float tree_norm_gt(const float (&a)[32], const int t,
                                              const int piv) {
  float ss[4] = {0.f, 0.f, 0.f, 0.f};
#pragma unroll
  for (int q = 0; q < 4; ++q)
#pragma unroll
    for (int k = 0; k < 8; ++k) {
      int kk = 8 * q + k;
      int r = t + 4 * kk;
      if (r > piv) ss[q] = fmaf(a[kk], a[kk], ss[q]);
    }
  return ((ss[0] + ss[1]) + ss[2]) + ss[3];
}

// ---------------- pre-split kernels (write d_ws; fragment-order layout) -------
// W_pre[m][ch] = 16KB block: hi 4096 ushorts [fg][row][8] then lo 4096.
__global__ __launch_bounds__(256) void presplit_w(const float* __restrict__ W,
                                                  unsigned short* __restrict__ Wp) {
  int id = blockIdx.x * 256 + threadIdx.x;
  int row = id & 127;
  int fg = (id >> 7) & 3;
  int mc = id >> 9;
  int mm = mc >> 4, ch = mc & 15;
  const float* src = W + ((size_t)mm * DOUT + row) * DIN + ch * 32 + fg * 8;
  bf16x8 hi, lo;
  unsigned short* hp = (unsigned short*)&hi;
  unsigned short* lp = (unsigned short*)&lo;
#pragma unroll
  for (int e = 0; e < 8; ++e) {
    float v = src[e];
    unsigned short h = f2bf(v);
    hp[e] = h;
    lp[e] = f2bf(v - bf2f(h));
  }
  unsigned short* dst = Wp + (size_t)mc * 8192 + (fg * 128 + row) * 8;
  *(bf16x8*)dst = hi;
  *(bf16x8*)(dst + 4096) = lo;
}

// X_pre[b][ch] = 8KB block: hi 2048 ushorts [fg][col][8], then lo 2048.
__global__ __launch_bounds__(256) void presplit_x(const float* __restrict__ X,
                                                  unsigned short* __restrict__ Xp) {
  int id = blockIdx.x * 256 + threadIdx.x;
  int col = id & 63;
  int fg = (id >> 6) & 3;
  int bc = id >> 8;
  int bb = bc >> 4, ch = bc & 15;
  const float* src = X + ((size_t)bb * DIN + ch * 32 + fg * 8) * QD + col;
  bf16x8 hi, lo;
  unsigned short* hp = (unsigned short*)&hi;
  unsigned short* lp = (unsigned short*)&lo;
#pragma unroll
  for (int e = 0; e < 8; ++e) {
    float v = src[(size_t)e * QD];
    unsigned short h = f2bf(v);
    hp[e] = h;
    lp[e] = f2bf(v - bf2f(h));
  }
  unsigned short* dst = Xp + (size_t)bc * 4096 + (fg * 64 + col) * 8;
  *(bf16x8*)dst = hi;
  *(bf16x8*)(dst + 2048) = lo;
}

// ---------------- shared-memory layouts ----------------
struct SmemPre { float Buf[64][65]; };             // handoff only (16.6 KB)
union SmemFall {
  struct {
    unsigned short Wh[DOUT][40];
    unsigned short Wl[DOUT][40];
    unsigned short Xh[QD][40];
    unsigned short Xl[QD][40];
  } g;
  float Buf[64][65];
};
template <bool PRE> struct SmemSel { using T = SmemPre; };
template <> struct SmemSel<false> { using T = SmemFall; };

// One block (256 thr = 4 waves) per matrix (m,b).
// GEMM (PRE): fragments loaded DIRECTLY global->VGPR (pre-split arrays are in
//   fragment order; 16B/lane, 256B/16-lane group). No LDS staging, no chunk
//   barriers. Register-lean: W frags live, X frags loaded per-tc.
// QR: R6 structure (1 barrier/step, DPP quad reduce, publish-ahead) with
//   tree-reduced dot/norm chains (critical path 128 -> ~45 cyc).
template <bool PRE>
__global__ __launch_bounds__(256, 5) void frmap_qr(
    const float* __restrict__ X, const float* __restrict__ W,
    float* __restrict__ out, const unsigned short* __restrict__ Wp,
    const unsigned short* __restrict__ Xp) {
  __shared__ __align__(16) typename SmemSel<PRE>::T U;
  __shared__ __align__(16) float Vq[2][4][36];
  __shared__ float Tau[QD];

  const int tid = threadIdx.x;
  const int l = tid & 63;                                   // lane
  const int w = __builtin_amdgcn_readfirstlane(tid >> 6);   // wave 0..3
  const int c = tid >> 2;                                   // QR column
  const int t = tid & 3;                                    // QR row class

  const int bid = blockIdx.x;  // m*256 + b
  const int m = bid >> 8;
  const int b = bid & 255;
  const float* Xb = X + (size_t)b * (DIN * QD);
  const float* Wm = W + (size_t)m * (DOUT * DIN);

  f32x4 acc[2][4];
#pragma unroll
  for (int tr = 0; tr < 2; ++tr)
#pragma unroll
    for (int tc = 0; tc < 4; ++tc)
      acc[tr][tc] = (f32x4){0.f, 0.f, 0.f, 0.f};

  const int fr = l & 15;  // row/col within 16x16 tile
  const int fg = l >> 4;  // k-group (8 bf16 each)

  if constexpr (PRE) {
    // ---------------- Phase 1 (PRE): direct-fragment MFMA GEMM
    const char* wsrc = (const char*)Wp + (size_t)(m * 16) * 16384;
    const char* xsrc = (const char*)Xp + (size_t)(b * 16) * 8192;
    const int woff = (fg * 128 + 32 * w + fr) * 16;  // + tr*256B
    const int xoff = (fg * 64 + fr) * 16;            // + tc*256B
    for (int ch = 0; ch < 16; ++ch) {
      bf16x8 ah0 = *(const bf16x8*)(wsrc + woff);
      bf16x8 al0 = *(const bf16x8*)(wsrc + 8192 + woff);
      bf16x8 ah1 = *(const bf16x8*)(wsrc + woff + 256);
      bf16x8 al1 = *(const bf16x8*)(wsrc + 8192 + woff + 256);
#pragma unroll
      for (int tc = 0; tc < 4; ++tc) {
        bf16x8 bh = *(const bf16x8*)(xsrc + xoff + tc * 256);
        bf16x8 bl = *(const bf16x8*)(xsrc + 4096 + xoff + tc * 256);
        acc[0][tc] = __builtin_amdgcn_mfma_f32_16x16x32_bf16(ah0, bh,
                                                             acc[0][tc], 0, 0, 0);
        acc[0][tc] = __builtin_amdgcn_mfma_f32_16x16x32_bf16(ah0, bl,
                                                             acc[0][tc], 0, 0, 0);
        acc[0][tc] = __builtin_amdgcn_mfma_f32_16x16x32_bf16(al0, bh,
                                                             acc[0][tc], 0, 0, 0);
        acc[1][tc] = __builtin_amdgcn_mfma_f32_16x16x32_bf16(ah1, bh,
                                                             acc[1][tc], 0, 0, 0);
        acc[1][tc] = __builtin_amdgcn_mfma_f32_16x16x32_bf16(ah1, bl,
                                                             acc[1][tc], 0, 0, 0);
        acc[1][tc] = __builtin_amdgcn_mfma_f32_16x16x32_bf16(al1, bh,
                                                             acc[1][tc], 0, 0, 0);
      }
      wsrc += 16384;
      xsrc += 8192;
    }
  } else {
    // ---------------- Phase 1 (fallback): in-kernel conversion GEMM (R8)
    for (int kc = 0; kc < DIN; kc += 32) {
      ushort4 wh[4], wl[4];
      int wrow[4], wkw[4];
#pragma unroll
      for (int i = 0; i < 4; ++i) {
        int f = 4 * tid + i;
        wrow[i] = f >> 3;
        wkw[i] = f & 7;
        float4 v = *(const float4*)(Wm + wrow[i] * DIN + kc + 4 * wkw[i]);
        float p[4] = {v.x, v.y, v.z, v.w};
        unsigned short* hp = (unsigned short*)&wh[i];
        unsigned short* lp = (unsigned short*)&wl[i];
#pragma unroll
        for (int e = 0; e < 4; ++e) {
          unsigned short hh = f2bf(p[e]);
          hp[e] = hh;
          lp[e] = f2bf(p[e] - bf2f(hh));
        }
      }
      unsigned short xh[8], xl[8];
#pragma unroll
      for (int j = 0; j < 8; ++j) {
        float xvj = Xb[(kc + w + 4 * j) * QD + l];
        unsigned short hh = f2bf(xvj);
        xh[j] = hh;
        xl[j] = f2bf(xvj - bf2f(hh));
      }
      __syncthreads();
#pragma unroll
      for (int i = 0; i < 4; ++i) {
        *(ushort4*)&U.g.Wh[wrow[i]][4 * wkw[i]] = wh[i];
        *(ushort4*)&U.g.Wl[wrow[i]][4 * wkw[i]] = wl[i];
      }
#pragma unroll
      for (int j = 0; j < 8; ++j) {
        U.g.Xh[l][w + 4 * j] = xh[j];
        U.g.Xl[l][w + 4 * j] = xl[j];
      }
      __syncthreads();
#pragma unroll
      for (int tr = 0; tr < 2; ++tr) {
        bf16x8 ah = *(const bf16x8*)&U.g.Wh[32 * w + 16 * tr + fr][8 * fg];
        bf16x8 al = *(const bf16x8*)&U.g.Wl[32 * w + 16 * tr + fr][8 * fg];
#pragma unroll
        for (int tc = 0; tc < 4; ++tc) {
          bf16x8 bh = *(const bf16x8*)&U.g.Xh[16 * tc + fr][8 * fg];
          bf16x8 bl = *(const bf16x8*)&U.g.Xl[16 * tc + fr][8 * fg];
          acc[tr][tc] = __builtin_amdgcn_mfma_f32_16x16x32_bf16(ah, bh,
                                                                acc[tr][tc], 0, 0, 0);
          acc[tr][tc] = __builtin_amdgcn_mfma_f32_16x16x32_bf16(ah, bl,
                                                                acc[tr][tc], 0, 0, 0);
          acc[tr][tc] = __builtin_amdgcn_mfma_f32_16x16x32_bf16(al, bh,
                                                                acc[tr][tc], 0, 0, 0);
        }
      }
    }
  }

  // ---------------- Phase 1.5: acc -> Buf -> QR ownership (c=tid>>2, t=tid&3)
  // C/D layout (m89-verified): col = lane&15, row = (lane>>4)*4 + reg.
  float a[32];
  __syncthreads();
  if (w < 2) {  // rows 0..63
#pragma unroll
    for (int tr = 0; tr < 2; ++tr)
#pragma unroll
      for (int tc = 0; tc < 4; ++tc)
#pragma unroll
        for (int v = 0; v < 4; ++v)
          U.Buf[32 * w + 16 * tr + 4 * fg + v][16 * tc + fr] = acc[tr][tc][v];
  }
  __syncthreads();
#pragma unroll
  for (int k = 0; k < 16; ++k) a[k] = U.Buf[t + 4 * k][c];
  __syncthreads();
  if (w >= 2) {  // rows 64..127
#pragma unroll
    for (int tr = 0; tr < 2; ++tr)
#pragma unroll
      for (int tc = 0; tc < 4; ++tc)
#pragma unroll
        for (int v = 0; v < 4; ++v)
          U.Buf[32 * (w - 2) + 16 * tr + 4 * fg + v][16 * tc + fr] =
              acc[tr][tc][v];
  }
  __syncthreads();
#pragma unroll
  for (int k = 16; k < 32; ++k) a[k] = U.Buf[t + 4 * k - 64][c];

  // ---------------- prologue: quad 0 makes tau0/invs0, scales, publishes V_0
  if (c == 0) {
    float myalpha = 0.f;
#pragma unroll
    for (int k = 0; k < 32; ++k)
      if (t + 4 * k == 0) myalpha = a[k];
    float xn2 = quadSum4(tree_norm_gt(a, t, 0));
    float alpha = qbc<0x00>(myalpha);
    float tau, invs;
    make_tau(xn2, alpha, tau, invs);
    if (t == 0) Tau[0] = tau;
    publish_col<true>(a, t, 0, invs, &Vq[0][t][0]);
  }
  __syncthreads();  // B0: V_0 / Tau[0] visible

  // ---------------- Phase 2a: sgeqr2 (1 barrier/step, publish-ahead)
  for (int j = 0; j < QD - 1; ++j) {
    if (c > j) {
      float taul = Tau[j];
      float vr[32];
      load_v(vr, &Vq[j & 1][t][0]);
      float wv = taul * quadSum4(tree_dot(vr, a));
#pragma unroll
      for (int k = 0; k < 32; ++k) a[k] = fmaf(-wv, vr[k], a[k]);
      if (c == j + 1) {  // tail: next pivot's tau/scale/publish
        float myalpha = 0.f;
#pragma unroll
        for (int k = 0; k < 32; ++k)
          if (t + 4 * k == j + 1) myalpha = a[k];  // static reg index
        float xn2 = quadSum4(tree_norm_gt(a, t, j + 1));
        float alpha;
        switch ((j + 1) & 3) {
          case 0:  alpha = qbc<0x00>(myalpha); break;
          case 1:  alpha = qbc<0x55>(myalpha); break;
          case 2:  alpha = qbc<0xAA>(myalpha); break;
          default: alpha = qbc<0xFF>(myalpha); break;
        }
        float tau, invs;
        make_tau(xn2, alpha, tau, invs);
        if (t == 0) Tau[j + 1] = tau;
        publish_col<true>(a, t, j + 1, invs, &Vq[(j + 1) & 1][t][0]);
      }
    }
    __syncthreads();
  }

  __syncthreads();  // phase boundary (protect Vq[1])

  // ---------------- Phase 2b: sorg2r (1 barrier/step, publish-ahead)
  for (int i = QD - 1; i >= 0; --i) {
    if (c > i) {
      float taul = Tau[i];
      float vr[32];
      load_v(vr, &Vq[i & 1][t][0]);
      float wv = taul * quadSum4(tree_dot(vr, a));
#pragma unroll
      for (int k = 0; k < 32; ++k) a[k] = fmaf(-wv, vr[k], a[k]);
    } else if (c == i) {
      float taul = Tau[i];
#pragma unroll
      for (int k = 0; k < 32; ++k) {
        int r = t + 4 * k;
        float val = a[k];
        float nv;
        if (r == i) nv = 1.f - taul;
        else if (r < i) nv = 0.f;
        else nv = -taul * val;
        a[k] = nv;
      }
    } else if (c == i - 1) {
      publish_col<false>(a, t, i - 1, 0.f, &Vq[(i - 1) & 1][t][0]);
    }
    if (i) __syncthreads();
  }

  // ---------------- Phase 3: store Q
  float* O = out + (size_t)bid * (DOUT * QD);
#pragma unroll
  for (int k = 0; k < 32; ++k) O[(t + 4 * k) * QD + c] = a[k];
}

extern "C" void kernel_launch(void* const* d_in, const int* in_sizes, int n_in,
                              void* d_out, int out_size, void* d_ws, size_t ws_size,
                              hipStream_t stream) {
  const float* X = (const float*)d_in[0];   // (256, 512, 64) fp32
  const float* W = (const float*)d_in[1];   // (16, 128, 512) fp32
  float* out = (float*)d_out;               // (4096, 128, 64) fp32

  const size_t needW = (size_t)NMAPS * 16 * 16384;  // 4 MiB
  const size_t needX = (size_t)256 * 16 * 8192;     // 32 MiB
  if (ws_size >= needW + needX) {
    unsigned short* Wp = (unsigned short*)d_ws;
    unsigned short* Xp = (unsigned short*)((char*)d_ws + needW);
    presplit_w<<<512, 256, 0, stream>>>(W, Wp);
    presplit_x<<<4096, 256, 0, stream>>>(X, Xp);
    frmap_qr<true><<<NMAPS * 256, 256, 0, stream>>>(X, W, out, Wp, Xp);
  } else {
    frmap_qr<false><<<NMAPS * 256, 256, 0, stream>>>(X, W, out, nullptr, nullptr);
  }
}

// Round 10
// 421.704 us; speedup vs baseline: 1.3682x; 1.3682x over previous
//
#include <hip/hip_runtime.h>
#include <math.h>

#define NMAPS 16
#define DIN 512
#define DOUT 128
#define QD 64

typedef __attribute__((ext_vector_type(8))) short bf16x8;  // 8 bf16 (4 VGPR)
typedef __attribute__((ext_vector_type(4))) float f32x4;

// bf16 split helpers (RNE). x = bf2f(hi) + bf2f(lo) + O(2^-18 |x|).
__device__ __forceinline__ unsigned short f2bf(float x) {
  unsigned int u = __float_as_uint(x);
  return (unsigned short)((u + 0x7FFFu + ((u >> 16) & 1u)) >> 16);
}
__device__ __forceinline__ float bf2f(unsigned short h) {
  return __uint_as_float(((unsigned int)h) << 16);
}

// DPP lane^1 / lane^2 within quad (VALU pipe).
__device__ __forceinline__ float qxor1(float x) {  // quad_perm {1,0,3,2} = 0xB1
  return __int_as_float(__builtin_amdgcn_update_dpp(
      0, __float_as_int(x), 0xB1, 0xF, 0xF, true));
}
__device__ __forceinline__ float qxor2(float x) {  // quad_perm {2,3,0,1} = 0x4E
  return __int_as_float(__builtin_amdgcn_update_dpp(
      0, __float_as_int(x), 0x4E, 0xF, 0xF, true));
}
// Butterfly sum over the 8-lane group (lanes 8g..8g+7). All 8 lanes get the
// same value (fp add is commutative, so mirrored orders agree bitwise).
__device__ __forceinline__ float groupSum8(float x) {
  x += qxor1(x);
  x += qxor2(x);
  x += __int_as_float(__builtin_amdgcn_ds_swizzle(
      __float_as_int(x), 0x101F));  // xor 4, and 0x1F
  return x;
}

// slarfg sign convention (LAPACK) — unchanged since R4.
__device__ __forceinline__ void make_tau(float xn2, float alpha, float& tau,
                                         float& invs) {
  if (xn2 == 0.f) { tau = 0.f; invs = 0.f; }
  else {
    float mag = sqrtf(alpha * alpha + xn2);
    float beta = (alpha >= 0.f) ? -mag : mag;
    tau = (beta - alpha) / beta;
    invs = 1.f / (alpha - beta);
  }
}

// 4x4 blocked tree dot over 16 elements (critical path ~8 FMA + 3 adds).
__device__ __forceinline__ float tree_dot16(const float (&x)[16],
                                            const float (&y)[16]) {
  float pp[4] = {0.f, 0.f, 0.f, 0.f};
#pragma unroll
  for (int q = 0; q < 4; ++q)
#pragma unroll
    for (int k = 0; k < 4; ++k)
      pp[q] = fmaf(x[4 * q + k], y[4 * q + k], pp[q]);
  return ((pp[0] + pp[1]) + pp[2]) + pp[3];
}

// Masked norm^2 over rows r = t+8k > piv, tree-reduced.
__device__ __forceinline__ float tree_norm_gt16(const float (&a)[16],
                                                const int t, const int piv) {
  float ss[4] = {0.f, 0.f, 0.f, 0.f};
#pragma unroll
  for (int q = 0; q < 4; ++q)
#pragma unroll
    for (int k = 0; k < 4; ++k) {
      int kk = 4 * q + k;
      int r = t + 8 * kk;
      if (r > piv) ss[q] = fmaf(a[kk], a[kk], ss[q]);
    }
  return ((ss[0] + ss[1]) + ss[2]) + ss[3];
}

template <bool SCALE>
__device__ __forceinline__ void publish_col16(float (&a)[16], const int t,
                                              const int piv, const float invs,
                                              float* __restrict__ Vrow) {
#pragma unroll
  for (int k4 = 0; k4 < 4; ++k4) {
    float4 v4;
    float* vv = (float*)&v4;
#pragma unroll
    for (int e = 0; e < 4; ++e) {
      int k = 4 * k4 + e;
      int r = t + 8 * k;
      float nv;
      if (r > piv) {
        if (SCALE) a[k] *= invs;
        nv = a[k];
      } else nv = (r == piv) ? 1.f : 0.f;
      vv[e] = nv;
    }
    *(float4*)&Vrow[4 * k4] = v4;
  }
}

__device__ __forceinline__ void load_v16(float (&vr)[16],
                                         const float* __restrict__ Vrow) {
#pragma unroll
  for (int k4 = 0; k4 < 4; ++k4) {
    float4 v4 = *(const float4*)&Vrow[4 * k4];
    vr[4 * k4 + 0] = v4.x; vr[4 * k4 + 1] = v4.y;
    vr[4 * k4 + 2] = v4.z; vr[4 * k4 + 3] = v4.w;
  }
}

// ---------------- pre-split kernels (write d_ws; fragment-order layout) -------
// W_pre[m][ch] = 16KB block: hi 4096 ushorts [fg][row][8] then lo 4096.
__global__ __launch_bounds__(256) void presplit_w(const float* __restrict__ W,
                                                  unsigned short* __restrict__ Wp) {
  int id = blockIdx.x * 256 + threadIdx.x;
  int row = id & 127;
  int fg = (id >> 7) & 3;
  int mc = id >> 9;
  int mm = mc >> 4, ch = mc & 15;
  const float* src = W + ((size_t)mm * DOUT + row) * DIN + ch * 32 + fg * 8;
  bf16x8 hi, lo;
  unsigned short* hp = (unsigned short*)&hi;
  unsigned short* lp = (unsigned short*)&lo;
#pragma unroll
  for (int e = 0; e < 8; ++e) {
    float v = src[e];
    unsigned short h = f2bf(v);
    hp[e] = h;
    lp[e] = f2bf(v - bf2f(h));
  }
  unsigned short* dst = Wp + (size_t)mc * 8192 + (fg * 128 + row) * 8;
  *(bf16x8*)dst = hi;
  *(bf16x8*)(dst + 4096) = lo;
}

// X_pre[b][ch] = 8KB block: hi 2048 ushorts [fg][col][8], then lo 2048.
__global__ __launch_bounds__(256) void presplit_x(const float* __restrict__ X,
                                                  unsigned short* __restrict__ Xp) {
  int id = blockIdx.x * 256 + threadIdx.x;
  int col = id & 63;
  int fg = (id >> 6) & 3;
  int bc = id >> 8;
  int bb = bc >> 4, ch = bc & 15;
  const float* src = X + ((size_t)bb * DIN + ch * 32 + fg * 8) * QD + col;
  bf16x8 hi, lo;
  unsigned short* hp = (unsigned short*)&hi;
  unsigned short* lp = (unsigned short*)&lo;
#pragma unroll
  for (int e = 0; e < 8; ++e) {
    float v = src[(size_t)e * QD];
    unsigned short h = f2bf(v);
    hp[e] = h;
    lp[e] = f2bf(v - bf2f(h));
  }
  unsigned short* dst = Xp + (size_t)bc * 4096 + (fg * 64 + col) * 8;
  *(bf16x8*)dst = hi;
  *(bf16x8*)(dst + 2048) = lo;
}

// One block (512 thr = 8 waves) per matrix (m,b).
// GEMM: 8 waves as 4 row-groups x 2 col-groups of 32x32 (2x2 tiles of 16x16);
//   fragments loaded directly global->VGPR from pre-split arrays.
// QR: thread (c = tid>>3, t = tid&7) owns rows r = t+8k (k<16) of column c in
//   a[16]; column reductions via 8-lane butterfly (2 DPP + 1 ds_swizzle);
//   1 barrier/step, publish-ahead, double-buffered V.
// Store: Buf round-trip so stores stay 256B-coalesced.
template <bool PRE>
__global__ __launch_bounds__(512, 6) void frmap_qr(
    const float* __restrict__ X, const float* __restrict__ W,
    float* __restrict__ out, const unsigned short* __restrict__ Wp,
    const unsigned short* __restrict__ Xp) {
  __shared__ __align__(16) float Buf[64][68];   // stride 68: bank = 4*row+col
  __shared__ __align__(16) float Vq[2][8][20];  // stride 20: conflict-free b128
  __shared__ float Tau[QD];

  const int tid = threadIdx.x;
  const int l = tid & 63;
  const int w = __builtin_amdgcn_readfirstlane(tid >> 6);  // wave 0..7
  const int rg = w >> 1;  // row-group 0..3 (rows 32rg..32rg+32)
  const int cg = w & 1;   // col-group 0..1 (cols 32cg..32cg+32)
  const int c = tid >> 3; // QR column 0..63
  const int t = tid & 7;  // QR row class (rows t+8k)
  const int fr = l & 15;  // row/col within 16x16 tile
  const int fg = l >> 4;  // k-group (8 bf16)

  const int bid = blockIdx.x;  // m*256 + b
  const int m = bid >> 8;
  const int b = bid & 255;
  const float* Xb = X + (size_t)b * (DIN * QD);
  const float* Wm = W + (size_t)m * (DOUT * DIN);

  f32x4 acc[2][2];
#pragma unroll
  for (int tr = 0; tr < 2; ++tr)
#pragma unroll
    for (int tc = 0; tc < 2; ++tc)
      acc[tr][tc] = (f32x4){0.f, 0.f, 0.f, 0.f};

  if constexpr (PRE) {
    // ---------------- Phase 1 (PRE): direct-fragment MFMA GEMM
    const char* wsrc = (const char*)Wp + (size_t)(m * 16) * 16384;
    const char* xsrc = (const char*)Xp + (size_t)(b * 16) * 8192;
    const int woff = (fg * 128 + 32 * rg + fr) * 16;  // + tr*256
    const int xoff = (fg * 64 + 32 * cg + fr) * 16;   // + tc*256
    for (int ch = 0; ch < 16; ++ch) {
      bf16x8 ah0 = *(const bf16x8*)(wsrc + woff);
      bf16x8 al0 = *(const bf16x8*)(wsrc + 8192 + woff);
      bf16x8 ah1 = *(const bf16x8*)(wsrc + woff + 256);
      bf16x8 al1 = *(const bf16x8*)(wsrc + 8192 + woff + 256);
      bf16x8 bh0 = *(const bf16x8*)(xsrc + xoff);
      bf16x8 bl0 = *(const bf16x8*)(xsrc + 4096 + xoff);
      bf16x8 bh1 = *(const bf16x8*)(xsrc + xoff + 256);
      bf16x8 bl1 = *(const bf16x8*)(xsrc + 4096 + xoff + 256);
      acc[0][0] = __builtin_amdgcn_mfma_f32_16x16x32_bf16(ah0, bh0, acc[0][0], 0, 0, 0);
      acc[0][0] = __builtin_amdgcn_mfma_f32_16x16x32_bf16(ah0, bl0, acc[0][0], 0, 0, 0);
      acc[0][0] = __builtin_amdgcn_mfma_f32_16x16x32_bf16(al0, bh0, acc[0][0], 0, 0, 0);
      acc[0][1] = __builtin_amdgcn_mfma_f32_16x16x32_bf16(ah0, bh1, acc[0][1], 0, 0, 0);
      acc[0][1] = __builtin_amdgcn_mfma_f32_16x16x32_bf16(ah0, bl1, acc[0][1], 0, 0, 0);
      acc[0][1] = __builtin_amdgcn_mfma_f32_16x16x32_bf16(al0, bh1, acc[0][1], 0, 0, 0);
      acc[1][0] = __builtin_amdgcn_mfma_f32_16x16x32_bf16(ah1, bh0, acc[1][0], 0, 0, 0);
      acc[1][0] = __builtin_amdgcn_mfma_f32_16x16x32_bf16(ah1, bl0, acc[1][0], 0, 0, 0);
      acc[1][0] = __builtin_amdgcn_mfma_f32_16x16x32_bf16(al1, bh0, acc[1][0], 0, 0, 0);
      acc[1][1] = __builtin_amdgcn_mfma_f32_16x16x32_bf16(ah1, bh1, acc[1][1], 0, 0, 0);
      acc[1][1] = __builtin_amdgcn_mfma_f32_16x16x32_bf16(ah1, bl1, acc[1][1], 0, 0, 0);
      acc[1][1] = __builtin_amdgcn_mfma_f32_16x16x32_bf16(al1, bh1, acc[1][1], 0, 0, 0);
      wsrc += 16384;
      xsrc += 8192;
    }
  } else {
    // ---------------- Phase 1 (fallback): in-kernel conversion, direct frags
    for (int ch = 0; ch < 16; ++ch) {
      int kc = ch * 32;
      bf16x8 ah[2], al[2], bh[2], bl[2];
#pragma unroll
      for (int tr = 0; tr < 2; ++tr) {
        const float* ws = Wm + (size_t)(32 * rg + 16 * tr + fr) * DIN + kc + 8 * fg;
        float4 v0 = *(const float4*)ws;
        float4 v1 = *(const float4*)(ws + 4);
        float p[8] = {v0.x, v0.y, v0.z, v0.w, v1.x, v1.y, v1.z, v1.w};
        unsigned short* hp = (unsigned short*)&ah[tr];
        unsigned short* lp = (unsigned short*)&al[tr];
#pragma unroll
        for (int e = 0; e < 8; ++e) {
          unsigned short h = f2bf(p[e]);
          hp[e] = h;
          lp[e] = f2bf(p[e] - bf2f(h));
        }
      }
#pragma unroll
      for (int tc = 0; tc < 2; ++tc) {
        const float* xs = Xb + (size_t)(kc + 8 * fg) * QD + 32 * cg + 16 * tc + fr;
        unsigned short* hp = (unsigned short*)&bh[tc];
        unsigned short* lp = (unsigned short*)&bl[tc];
#pragma unroll
        for (int e = 0; e < 8; ++e) {
          float v = xs[(size_t)e * QD];
          unsigned short h = f2bf(v);
          hp[e] = h;
          lp[e] = f2bf(v - bf2f(h));
        }
      }
#pragma unroll
      for (int tr = 0; tr < 2; ++tr)
#pragma unroll
        for (int tc = 0; tc < 2; ++tc) {
          acc[tr][tc] = __builtin_amdgcn_mfma_f32_16x16x32_bf16(ah[tr], bh[tc], acc[tr][tc], 0, 0, 0);
          acc[tr][tc] = __builtin_amdgcn_mfma_f32_16x16x32_bf16(ah[tr], bl[tc], acc[tr][tc], 0, 0, 0);
          acc[tr][tc] = __builtin_amdgcn_mfma_f32_16x16x32_bf16(al[tr], bh[tc], acc[tr][tc], 0, 0, 0);
        }
    }
  }

  // ---------------- Phase 1.5: acc -> Buf -> QR ownership
  // C/D layout (m89): col = 16tc'+(lane&15), row = 4*(lane>>4) + reg.
  float a[16];
  if (rg < 2) {  // rows 0..63
#pragma unroll
    for (int tr = 0; tr < 2; ++tr)
#pragma unroll
      for (int tc = 0; tc < 2; ++tc)
#pragma unroll
        for (int v = 0; v < 4; ++v)
          Buf[32 * rg + 16 * tr + 4 * fg + v][32 * cg + 16 * tc + fr] = acc[tr][tc][v];
  }
  __syncthreads();
#pragma unroll
  for (int k = 0; k < 8; ++k) a[k] = Buf[t + 8 * k][c];
  __syncthreads();
  if (rg >= 2) {  // rows 64..127
#pragma unroll
    for (int tr = 0; tr < 2; ++tr)
#pragma unroll
      for (int tc = 0; tc < 2; ++tc)
#pragma unroll
        for (int v = 0; v < 4; ++v)
          Buf[32 * (rg - 2) + 16 * tr + 4 * fg + v][32 * cg + 16 * tc + fr] = acc[tr][tc][v];
  }
  __syncthreads();
#pragma unroll
  for (int k = 8; k < 16; ++k) a[k] = Buf[t + 8 * k - 64][c];

  // ---------------- prologue: group c==0 makes tau0/invs0, scales, publishes
  if (c == 0) {
    float myalpha = 0.f;
#pragma unroll
    for (int k = 0; k < 16; ++k)
      if (t + 8 * k == 0) myalpha = a[k];
    float xn2 = groupSum8(tree_norm_gt16(a, t, 0));
    float alpha = groupSum8(myalpha);  // exact: zeros elsewhere
    float tau, invs;
    make_tau(xn2, alpha, tau, invs);
    if (t == 0) Tau[0] = tau;
    publish_col16<true>(a, t, 0, invs, &Vq[0][t][0]);
  }
  __syncthreads();  // B0: V_0 / Tau[0] visible

  // ---------------- Phase 2a: sgeqr2 (1 barrier/step, publish-ahead)
  for (int j = 0; j < QD - 1; ++j) {
    if (c > j) {
      float taul = Tau[j];
      float vr[16];
      load_v16(vr, &Vq[j & 1][t][0]);
      float wv = taul * groupSum8(tree_dot16(vr, a));
#pragma unroll
      for (int k = 0; k < 16; ++k) a[k] = fmaf(-wv, vr[k], a[k]);
      if (c == j + 1) {  // tail: next pivot's tau/scale/publish
        float myalpha = 0.f;
#pragma unroll
        for (int k = 0; k < 16; ++k)
          if (t + 8 * k == j + 1) myalpha = a[k];  // static reg index
        float xn2 = groupSum8(tree_norm_gt16(a, t, j + 1));
        float alpha = groupSum8(myalpha);
        float tau, invs;
        make_tau(xn2, alpha, tau, invs);
        if (t == 0) Tau[j + 1] = tau;
        publish_col16<true>(a, t, j + 1, invs, &Vq[(j + 1) & 1][t][0]);
      }
    }
    __syncthreads();
  }

  __syncthreads();  // phase boundary

  // ---------------- Phase 2b: sorg2r (1 barrier/step, publish-ahead)
  for (int i = QD - 1; i >= 0; --i) {
    if (c > i) {
      float taul = Tau[i];
      float vr[16];
      load_v16(vr, &Vq[i & 1][t][0]);
      float wv = taul * groupSum8(tree_dot16(vr, a));
#pragma unroll
      for (int k = 0; k < 16; ++k) a[k] = fmaf(-wv, vr[k], a[k]);
    } else if (c == i) {  // own column: 0 / 1-tau / -tau*v
      float taul = Tau[i];
#pragma unroll
      for (int k = 0; k < 16; ++k) {
        int r = t + 8 * k;
        float val = a[k];
        float nv;
        if (r == i) nv = 1.f - taul;
        else if (r < i) nv = 0.f;
        else nv = -taul * val;
        a[k] = nv;
      }
    } else if (c == i - 1) {  // idle group publishes V_{i-1}
      publish_col16<false>(a, t, i - 1, 0.f, &Vq[(i - 1) & 1][t][0]);
    }
    if (i) __syncthreads();
  }

  // ---------------- Phase 3: store via Buf (256B-coalesced)
  float* O = out + (size_t)bid * (DOUT * QD);
#pragma unroll
  for (int k = 0; k < 8; ++k) Buf[t + 8 * k][c] = a[k];
  __syncthreads();
#pragma unroll
  for (int i = 0; i < 8; ++i) {
    int r = 8 * w + i;
    O[r * QD + l] = Buf[r][l];
  }
  __syncthreads();
#pragma unroll
  for (int k = 8; k < 16; ++k) Buf[t + 8 * k - 64][c] = a[k];
  __syncthreads();
#pragma unroll
  for (int i = 0; i < 8; ++i) {
    int r = 8 * w + i;
    O[(64 + r) * QD + l] = Buf[r][l];
  }
}

extern "C" void kernel_launch(void* const* d_in, const int* in_sizes, int n_in,
                              void* d_out, int out_size, void* d_ws, size_t ws_size,
                              hipStream_t stream) {
  const float* X = (const float*)d_in[0];   // (256, 512, 64) fp32
  const float* W = (const float*)d_in[1];   // (16, 128, 512) fp32
  float* out = (float*)d_out;               // (4096, 128, 64) fp32

  const size_t needW = (size_t)NMAPS * 16 * 16384;  // 4 MiB
  const size_t needX = (size_t)256 * 16 * 8192;     // 32 MiB
  if (ws_size >= needW + needX) {
    unsigned short* Wp = (unsigned short*)d_ws;
    unsigned short* Xp = (unsigned short*)((char*)d_ws + needW);
    presplit_w<<<512, 256, 0, stream>>>(W, Wp);
    presplit_x<<<4096, 256, 0, stream>>>(X, Xp);
    frmap_qr<true><<<NMAPS * 256, 512, 0, stream>>>(X, W, out, Wp, Xp);
  } else {
    frmap_qr<false><<<NMAPS * 256, 512, 0, stream>>>(X, W, out, nullptr, nullptr);
  }
}